// Round 4
// baseline (72.484 us; speedup 1.0000x reference)
//
#include <hip/hip_runtime.h>
#include <math.h>

#define PI_F 3.14159265358979323846f
#define INV_2PI_D 0.15915494309189535

// compiler fence + wait: all prior LDS ops complete before any later ones issue
#define LDSYNC() asm volatile("s_waitcnt lgkmcnt(0)" ::: "memory")

// pad: a = e + e/16. All four transpose phases are <=2-way banked (free).
__device__ __forceinline__ int pad(int e) { return e + (e >> 4); }

__device__ __forceinline__ void bfly(float& ar, float& ai, float& br, float& bi,
                                     float wr, float wi) {
    const float tr = wr * br - wi * bi;
    const float ti = wr * bi + wi * br;
    br = ar - tr; bi = ai - ti;
    ar = ar + tr; ai = ai + ti;
}

__device__ __forceinline__ void fft_row(
    const float* __restrict__ xre, const float* __restrict__ xim,
    float* __restrict__ yre, float* __restrict__ yim,
    float* __restrict__ s,              // 1088 floats, private to this wave
    int row)
{
    const int lane = (int)(threadIdx.x & 63u);
    const size_t base = (size_t)row << 10;

    float re[16], im[16];

    // ---- bit-reversed loads: for fixed r, rev6(lane) permutes one 256B
    // segment -> fully coalesced despite being "scattered".
    const int rev6l = (int)(__brev((unsigned)lane) >> 26);
    const int REV4[16] = {0,8,4,12,2,10,6,14,1,9,5,13,3,11,7,15};
#pragma unroll
    for (int r = 0; r < 16; ++r) {
        const int a = REV4[r] * 64 + rev6l;
        re[r] = xre[base + a];
        im[r] = xim[base + a];
    }

    // ---- L1 stages s=1,2,4,8 (reg-local), exact constant twiddles
    const float W8R[8] = {1.f, 0.9238795325112867f, 0.7071067811865476f,
                          0.3826834323650898f, 0.f, -0.3826834323650898f,
                          -0.7071067811865476f, -0.9238795325112867f};
    const float W8I[8] = {0.f, -0.3826834323650898f, -0.7071067811865476f,
                          -0.9238795325112867f, -1.f, -0.9238795325112867f,
                          -0.7071067811865476f, -0.3826834323650898f};
#pragma unroll
    for (int st = 0; st < 4; ++st) {
        const int S = 1 << st;
#pragma unroll
        for (int rl = 0; rl < 16; ++rl) {
            if (rl & S) continue;
            const int k8 = (rl & (S - 1)) * (8 >> st);
            bfly(re[rl], im[rl], re[rl | S], im[rl | S], W8R[k8], W8I[k8]);
        }
    }

    const int hi = (lane >> 4) << 8;
    const int lo = lane & 15;

    // ---- T1: L1 (e=lane*16+r) -> L3 (e=(lane>>4)*256+r*16+(lane&15))
    // split re-pass / im-pass, one 1088-float buffer
#pragma unroll
    for (int r = 0; r < 16; ++r) s[pad(lane * 16 + r)] = re[r];
    LDSYNC();
#pragma unroll
    for (int r = 0; r < 16; ++r) re[r] = s[pad(hi + (r << 4) + lo)];
    LDSYNC();
#pragma unroll
    for (int r = 0; r < 16; ++r) s[pad(lane * 16 + r)] = im[r];
    LDSYNC();
#pragma unroll
    for (int r = 0; r < 16; ++r) im[r] = s[pad(hi + (r << 4) + lo)];
    LDSYNC();

    // ---- L3 twiddles: 8 sincos (s=128), squared down to 64,32,16
    const float l16f = (float)lo;
    float c8a[8], s8a[8];
#pragma unroll
    for (int m = 0; m < 8; ++m) {
        const float ang = -(PI_F / 128.0f) * (16.0f * (float)m + l16f);
        __sincosf(ang, &s8a[m], &c8a[m]);
    }
    float c4a[4], s4a[4];
#pragma unroll
    for (int m = 0; m < 4; ++m) { c4a[m] = c8a[m]*c8a[m] - s8a[m]*s8a[m]; s4a[m] = 2.0f*c8a[m]*s8a[m]; }
    float c2a[2], s2a[2];
#pragma unroll
    for (int m = 0; m < 2; ++m) { c2a[m] = c4a[m]*c4a[m] - s4a[m]*s4a[m]; s2a[m] = 2.0f*c4a[m]*s4a[m]; }
    const float c1a = c2a[0]*c2a[0] - s2a[0]*s2a[0];
    const float s1a = 2.0f*c2a[0]*s2a[0];

#pragma unroll
    for (int rl = 0; rl < 16; ++rl) if (!(rl & 1))
        bfly(re[rl], im[rl], re[rl|1], im[rl|1], c1a, s1a);
#pragma unroll
    for (int rl = 0; rl < 16; ++rl) if (!(rl & 2))
        bfly(re[rl], im[rl], re[rl|2], im[rl|2], c2a[rl & 1], s2a[rl & 1]);
#pragma unroll
    for (int rl = 0; rl < 16; ++rl) if (!(rl & 4))
        bfly(re[rl], im[rl], re[rl|4], im[rl|4], c4a[rl & 3], s4a[rl & 3]);
#pragma unroll
    for (int rl = 0; rl < 16; ++rl) if (!(rl & 8))
        bfly(re[rl], im[rl], re[rl|8], im[rl|8], c8a[rl & 7], s8a[rl & 7]);

    // ---- T2: L3 -> L2 (e=r*64+lane), split passes
#pragma unroll
    for (int r = 0; r < 16; ++r) s[pad(hi + (r << 4) + lo)] = re[r];
    LDSYNC();
#pragma unroll
    for (int r = 0; r < 16; ++r) re[r] = s[pad((r << 6) + lane)];
    LDSYNC();
#pragma unroll
    for (int r = 0; r < 16; ++r) s[pad(hi + (r << 4) + lo)] = im[r];
    LDSYNC();
#pragma unroll
    for (int r = 0; r < 16; ++r) im[r] = s[pad((r << 6) + lane)];
    LDSYNC();

    // ---- L2 twiddles: 8 sincos (s=512), squared for s=256
    const float lf = (float)lane;
    float cz8[8], sz8[8];
#pragma unroll
    for (int m = 0; m < 8; ++m) {
        const float ang = -(PI_F / 512.0f) * (64.0f * (float)m + lf);
        __sincosf(ang, &sz8[m], &cz8[m]);
    }
    float cz4[4], sz4[4];
#pragma unroll
    for (int m = 0; m < 4; ++m) { cz4[m] = cz8[m]*cz8[m] - sz8[m]*sz8[m]; sz4[m] = 2.0f*cz8[m]*sz8[m]; }

#pragma unroll
    for (int rl = 0; rl < 16; ++rl) if (!(rl & 4))
        bfly(re[rl], im[rl], re[rl|4], im[rl|4], cz4[rl & 3], sz4[rl & 3]);
#pragma unroll
    for (int rl = 0; rl < 16; ++rl) if (!(rl & 8))
        bfly(re[rl], im[rl], re[rl|8], im[rl|8], cz8[rl & 7], sz8[rl & 7]);

    // ---- coalesced stores (fixed r -> one contiguous 256B segment)
#pragma unroll
    for (int r = 0; r < 16; ++r) {
        yre[base + (r << 6) + lane] = re[r];
        yim[base + (r << 6) + lane] = im[r];
    }
}

// one-time table: correctly-rounded fl32(log n) and fl32(1/sqrt n), n=1..1024
__global__ __launch_bounds__(256) void table_kernel(float* __restrict__ ws) {
    const int i = (int)(blockIdx.x * 256 + threadIdx.x);
    if (i < 1024) {
        const double nd = (double)(i + 1);
        ws[i]        = (float)log(nd);
        ws[1024 + i] = (float)(1.0 / sqrt(nd));
    }
}

__device__ void z_eval(const float* __restrict__ tin, float* __restrict__ zout,
                       const float* __restrict__ ws, int zblock, int n,
                       float* __restrict__ buf)
{
    // copy 2048-float table ws -> LDS (float4, coalesced)
    for (int i = (int)threadIdx.x; i < 512; i += 256)
        reinterpret_cast<float4*>(buf)[i] = reinterpret_cast<const float4*>(ws)[i];
    __syncthreads();
    const float* slog = buf;
    const float* srsq = buf + 1024;

    const int gid = zblock * 256 + (int)threadIdx.x;
    if (gid >= n) return;

    const float t  = tin[gid];
    const float th = __fmul_rn(t, 0.5f);
    const float logt = (float)log((double)t);
    float theta = __fsub_rn(__fsub_rn(__fmul_rn(th, __fsub_rn(logt, 1.8378770664093453f)), th),
                            0.39269908169872414f);
    theta = __fadd_rn(theta, __fdiv_rn(1.0f, __fmul_rn(48.0f, t)));

    int nt = (int)sqrtf(__fdiv_rn(t, 6.283185307179586f));
    nt = min(max(nt, 10), 1024);

    float acc = 0.0f;
    for (int i = 0; i < nt; ++i) {
        const float p = __fsub_rn(__fmul_rn(t, slog[i]), theta);
        const double rev = (double)p * INV_2PI_D;
        const double fr  = rev - rint(rev);            // |fr| <= 0.5 revolutions
        const float  c   = __builtin_amdgcn_cosf((float)fr);
        acc = __fmaf_rn(srsq[i], c, acc);
    }
    zout[gid] = __fmul_rn(2.0f, acc);
}

__global__ __launch_bounds__(256, 8) void fused_kernel(
    const float* __restrict__ xre, const float* __restrict__ xim,
    const float* __restrict__ tin, const float* __restrict__ ws,
    float* __restrict__ yre, float* __restrict__ yim, float* __restrict__ zout,
    int z_blocks, int nrows, int nz)
{
    __shared__ float s[4][1088];     // 17408 B -> 8 blocks/CU (32 waves/CU)

    const int b = (int)blockIdx.x;
    if (b < z_blocks) {
        z_eval(tin, zout, ws, b, nz, &s[0][0]);
    } else {
        const int wid = (int)(threadIdx.x >> 6);
        const int row = ((b - z_blocks) << 2) | wid;
        if (row < nrows)
            fft_row(xre, xim, yre, yim, s[wid], row);
    }
}

extern "C" void kernel_launch(void* const* d_in, const int* in_sizes, int n_in,
                              void* d_out, int out_size, void* d_ws, size_t ws_size,
                              hipStream_t stream)
{
    const float* xre = (const float*)d_in[0];
    const float* xim = (const float*)d_in[1];
    const float* t   = (const float*)d_in[2];

    const size_t nfft = (size_t)in_sizes[0];          // 16384*1024
    const int nrows = (int)(nfft >> 10);              // 16384
    const int nz    = in_sizes[2];                    // 262144

    float* yre = (float*)d_out;
    float* yim = yre + nfft;
    float* z   = yre + 2 * nfft;
    float* ws  = (float*)d_ws;                        // 2048 floats of table

    table_kernel<<<4, 256, 0, stream>>>(ws);

    const int f_blocks = (nrows + 3) >> 2;
    const int z_blocks = (nz + 255) >> 8;
    fused_kernel<<<z_blocks + f_blocks, 256, 0, stream>>>(
        xre, xim, t, ws, yre, yim, z, z_blocks, nrows, nz);
}

// Round 6
// 58.601 us; speedup vs baseline: 1.2369x; 1.2369x over previous
//
#include <hip/hip_runtime.h>
#include <math.h>

#define PI_F 3.14159265358979323846f
#define INV_2PI_D 0.15915494309189535

// Cross-lane LDS transpose fence. The waitcnt orders the HW; the "memory"
// clobber is the essential part: it stops the compiler from reordering the
// write-pass and read-pass, which it may otherwise legally do because the
// cross-lane dependence is invisible in per-thread SIMT semantics (round-5
// failure mode).
#define LDSYNC() asm volatile("s_waitcnt lgkmcnt(0)" ::: "memory")

// pad: a = e + e/16. All four transpose phases are <=2-way banked (free).
__device__ __forceinline__ int pad(int e) { return e + (e >> 4); }

__device__ __forceinline__ void bfly(float& ar, float& ai, float& br, float& bi,
                                     float wr, float wi) {
    const float tr = wr * br - wi * bi;
    const float ti = wr * bi + wi * br;
    br = ar - tr; bi = ai - ti;
    ar = ar + tr; ai = ai + ti;
}

__device__ __forceinline__ void fft_row(
    const float* __restrict__ xre, const float* __restrict__ xim,
    float* __restrict__ yre, float* __restrict__ yim,
    float* __restrict__ s,              // 1088 floats, private to this wave
    int row)
{
    const int lane = (int)(threadIdx.x & 63u);
    const size_t base = (size_t)row << 10;

    float re[16], im[16];

    // ---- bit-reversed loads: for fixed r, rev6(lane) permutes one 256B
    // segment -> fully coalesced despite being "scattered".
    const int rev6l = (int)(__brev((unsigned)lane) >> 26);
    const int REV4[16] = {0,8,4,12,2,10,6,14,1,9,5,13,3,11,7,15};
#pragma unroll
    for (int r = 0; r < 16; ++r) {
        const int a = REV4[r] * 64 + rev6l;
        re[r] = xre[base + a];
        im[r] = xim[base + a];
    }

    // ---- L1 stages s=1,2,4,8 (reg-local), exact constant twiddles
    const float W8R[8] = {1.f, 0.9238795325112867f, 0.7071067811865476f,
                          0.3826834323650898f, 0.f, -0.3826834323650898f,
                          -0.7071067811865476f, -0.9238795325112867f};
    const float W8I[8] = {0.f, -0.3826834323650898f, -0.7071067811865476f,
                          -0.9238795325112867f, -1.f, -0.9238795325112867f,
                          -0.7071067811865476f, -0.3826834323650898f};
#pragma unroll
    for (int st = 0; st < 4; ++st) {
        const int S = 1 << st;
#pragma unroll
        for (int rl = 0; rl < 16; ++rl) {
            if (rl & S) continue;
            const int k8 = (rl & (S - 1)) * (8 >> st);
            bfly(re[rl], im[rl], re[rl | S], im[rl | S], W8R[k8], W8I[k8]);
        }
    }

    const int hi = (lane >> 4) << 8;
    const int lo = lane & 15;

    // ---- T1: L1 (e=lane*16+r) -> L3 (e=(lane>>4)*256+r*16+(lane&15))
    // split re-pass / im-pass, one 1088-float buffer
#pragma unroll
    for (int r = 0; r < 16; ++r) s[pad(lane * 16 + r)] = re[r];
    LDSYNC();
#pragma unroll
    for (int r = 0; r < 16; ++r) re[r] = s[pad(hi + (r << 4) + lo)];
    LDSYNC();
#pragma unroll
    for (int r = 0; r < 16; ++r) s[pad(lane * 16 + r)] = im[r];
    LDSYNC();
#pragma unroll
    for (int r = 0; r < 16; ++r) im[r] = s[pad(hi + (r << 4) + lo)];
    LDSYNC();

    // ---- L3 twiddles: 8 sincos (s=128), squared down to 64,32,16
    const float l16f = (float)lo;
    float c8a[8], s8a[8];
#pragma unroll
    for (int m = 0; m < 8; ++m) {
        const float ang = -(PI_F / 128.0f) * (16.0f * (float)m + l16f);
        __sincosf(ang, &s8a[m], &c8a[m]);
    }
    float c4a[4], s4a[4];
#pragma unroll
    for (int m = 0; m < 4; ++m) { c4a[m] = c8a[m]*c8a[m] - s8a[m]*s8a[m]; s4a[m] = 2.0f*c8a[m]*s8a[m]; }
    float c2a[2], s2a[2];
#pragma unroll
    for (int m = 0; m < 2; ++m) { c2a[m] = c4a[m]*c4a[m] - s4a[m]*s4a[m]; s2a[m] = 2.0f*c4a[m]*s4a[m]; }
    const float c1a = c2a[0]*c2a[0] - s2a[0]*s2a[0];
    const float s1a = 2.0f*c2a[0]*s2a[0];

#pragma unroll
    for (int rl = 0; rl < 16; ++rl) if (!(rl & 1))
        bfly(re[rl], im[rl], re[rl|1], im[rl|1], c1a, s1a);
#pragma unroll
    for (int rl = 0; rl < 16; ++rl) if (!(rl & 2))
        bfly(re[rl], im[rl], re[rl|2], im[rl|2], c2a[rl & 1], s2a[rl & 1]);
#pragma unroll
    for (int rl = 0; rl < 16; ++rl) if (!(rl & 4))
        bfly(re[rl], im[rl], re[rl|4], im[rl|4], c4a[rl & 3], s4a[rl & 3]);
#pragma unroll
    for (int rl = 0; rl < 16; ++rl) if (!(rl & 8))
        bfly(re[rl], im[rl], re[rl|8], im[rl|8], c8a[rl & 7], s8a[rl & 7]);

    // ---- T2: L3 -> L2 (e=r*64+lane), split passes
#pragma unroll
    for (int r = 0; r < 16; ++r) s[pad(hi + (r << 4) + lo)] = re[r];
    LDSYNC();
#pragma unroll
    for (int r = 0; r < 16; ++r) re[r] = s[pad((r << 6) + lane)];
    LDSYNC();
#pragma unroll
    for (int r = 0; r < 16; ++r) s[pad(hi + (r << 4) + lo)] = im[r];
    LDSYNC();
#pragma unroll
    for (int r = 0; r < 16; ++r) im[r] = s[pad((r << 6) + lane)];
    LDSYNC();

    // ---- L2 twiddles: 8 sincos (s=512), squared for s=256
    const float lf = (float)lane;
    float cz8[8], sz8[8];
#pragma unroll
    for (int m = 0; m < 8; ++m) {
        const float ang = -(PI_F / 512.0f) * (64.0f * (float)m + lf);
        __sincosf(ang, &sz8[m], &cz8[m]);
    }
    float cz4[4], sz4[4];
#pragma unroll
    for (int m = 0; m < 4; ++m) { cz4[m] = cz8[m]*cz8[m] - sz8[m]*sz8[m]; sz4[m] = 2.0f*cz8[m]*sz8[m]; }

#pragma unroll
    for (int rl = 0; rl < 16; ++rl) if (!(rl & 4))
        bfly(re[rl], im[rl], re[rl|4], im[rl|4], cz4[rl & 3], sz4[rl & 3]);
#pragma unroll
    for (int rl = 0; rl < 16; ++rl) if (!(rl & 8))
        bfly(re[rl], im[rl], re[rl|8], im[rl|8], cz8[rl & 7], sz8[rl & 7]);

    // ---- coalesced stores (fixed r -> one contiguous 256B segment)
#pragma unroll
    for (int r = 0; r < 16; ++r) {
        yre[base + (r << 6) + lane] = re[r];
        yim[base + (r << 6) + lane] = im[r];
    }
}

// one-time table: correctly-rounded fl32(log n) and fl32(1/sqrt n), n=1..1024
__global__ __launch_bounds__(256) void table_kernel(float* __restrict__ ws) {
    const int i = (int)(blockIdx.x * 256 + threadIdx.x);
    if (i < 1024) {
        const double nd = (double)(i + 1);
        ws[i]        = (float)log(nd);
        ws[1024 + i] = (float)(1.0 / sqrt(nd));
    }
}

__device__ void z_eval(const float* __restrict__ tin, float* __restrict__ zout,
                       const float* __restrict__ ws, int zblock, int n,
                       float* __restrict__ buf)
{
    // copy 2048-float table ws -> LDS (float4, coalesced)
    for (int i = (int)threadIdx.x; i < 512; i += 256)
        reinterpret_cast<float4*>(buf)[i] = reinterpret_cast<const float4*>(ws)[i];
    __syncthreads();
    const float* slog = buf;
    const float* srsq = buf + 1024;

    const int gid = zblock * 256 + (int)threadIdx.x;
    if (gid >= n) return;

    const float t  = tin[gid];
    const float th = __fmul_rn(t, 0.5f);
    const float logt = (float)log((double)t);
    float theta = __fsub_rn(__fsub_rn(__fmul_rn(th, __fsub_rn(logt, 1.8378770664093453f)), th),
                            0.39269908169872414f);
    theta = __fadd_rn(theta, __fdiv_rn(1.0f, __fmul_rn(48.0f, t)));

    int nt = (int)sqrtf(__fdiv_rn(t, 6.283185307179586f));
    nt = min(max(nt, 10), 1024);

    float acc = 0.0f;
    for (int i = 0; i < nt; ++i) {
        const float p = __fsub_rn(__fmul_rn(t, slog[i]), theta);
        const double rev = (double)p * INV_2PI_D;
        const double fr  = rev - rint(rev);            // |fr| <= 0.5 revolutions
        const float  c   = __builtin_amdgcn_cosf((float)fr);
        acc = __fmaf_rn(srsq[i], c, acc);
    }
    zout[gid] = __fmul_rn(2.0f, acc);
}

__global__ __launch_bounds__(256, 6) void fused_kernel(
    const float* __restrict__ xre, const float* __restrict__ xim,
    const float* __restrict__ tin, const float* __restrict__ ws,
    float* __restrict__ yre, float* __restrict__ yim, float* __restrict__ zout,
    int z_blocks, int nrows, int nz)
{
    __shared__ float s[4][1088];     // 17408 B/block -> 6 blocks/CU (VGPR cap 85)

    const int b = (int)blockIdx.x;
    if (b < z_blocks) {
        z_eval(tin, zout, ws, b, nz, &s[0][0]);
    } else {
        const int wid = (int)(threadIdx.x >> 6);
        const int row = ((b - z_blocks) << 2) | wid;
        if (row < nrows)
            fft_row(xre, xim, yre, yim, s[wid], row);
    }
}

extern "C" void kernel_launch(void* const* d_in, const int* in_sizes, int n_in,
                              void* d_out, int out_size, void* d_ws, size_t ws_size,
                              hipStream_t stream)
{
    const float* xre = (const float*)d_in[0];
    const float* xim = (const float*)d_in[1];
    const float* t   = (const float*)d_in[2];

    const size_t nfft = (size_t)in_sizes[0];          // 16384*1024
    const int nrows = (int)(nfft >> 10);              // 16384
    const int nz    = in_sizes[2];                    // 262144

    float* yre = (float*)d_out;
    float* yim = yre + nfft;
    float* z   = yre + 2 * nfft;
    float* ws  = (float*)d_ws;                        // 2048 floats of table

    table_kernel<<<4, 256, 0, stream>>>(ws);

    const int f_blocks = (nrows + 3) >> 2;
    const int z_blocks = (nz + 255) >> 8;
    fused_kernel<<<z_blocks + f_blocks, 256, 0, stream>>>(
        xre, xim, t, ws, yre, yim, z, z_blocks, nrows, nz);
}

// Round 7
// 58.124 us; speedup vs baseline: 1.2471x; 1.0082x over previous
//
#include <hip/hip_runtime.h>
#include <math.h>

#define INV_2PI_D 0.15915494309189535

// Cross-lane LDS transpose fence. The waitcnt orders the HW; the "memory"
// clobber stops the compiler from reordering the write-pass and read-pass
// (cross-lane dependence is invisible in per-thread SIMT semantics).
#define LDSYNC() asm volatile("s_waitcnt lgkmcnt(0)" ::: "memory")

// pad: a = e + e/16. All four transpose phases are <=2-way banked (free).
__device__ __forceinline__ int pad(int e) { return e + (e >> 4); }

__device__ __forceinline__ void bfly(float& ar, float& ai, float& br, float& bi,
                                     float wr, float wi) {
    const float tr = wr * br - wi * bi;
    const float ti = wr * bi + wi * br;
    br = ar - tr; bi = ai - ti;
    ar = ar + tr; ai = ai + ti;
}

// w = exp(2*pi*i * rev): hardware v_sin/v_cos take REVOLUTIONS (sin(S0*2pi)).
// Twiddle revs are -k/2^m -- exactly representable, no range reduction needed.
__device__ __forceinline__ void wrev(float rev, float& c, float& s) {
    s = __builtin_amdgcn_sinf(rev);
    c = __builtin_amdgcn_cosf(rev);
}

__device__ __forceinline__ void fft_row(
    const float* __restrict__ xre, const float* __restrict__ xim,
    float* __restrict__ yre, float* __restrict__ yim,
    float* __restrict__ s,              // 1088 floats, private to this wave
    int row)
{
    const int lane = (int)(threadIdx.x & 63u);
    const size_t base = (size_t)row << 10;

    float re[16], im[16];

    // ---- bit-reversed loads: for fixed r, rev6(lane) permutes one 256B
    // segment -> fully coalesced despite being "scattered".
    const int rev6l = (int)(__brev((unsigned)lane) >> 26);
    const int REV4[16] = {0,8,4,12,2,10,6,14,1,9,5,13,3,11,7,15};
#pragma unroll
    for (int r = 0; r < 16; ++r) {
        const int a = REV4[r] * 64 + rev6l;
        re[r] = xre[base + a];
        im[r] = xim[base + a];
    }

    const int lo = lane & 15;
    const int hi = (lane >> 4) << 8;
    const float lof = (float)lo;

    // ---- L3-stage twiddles, hoisted here to overlap global-load latency.
    // Stage s pairs k -> w = exp(-2pi*i*k/(2s)); rev = -k/(2s) exact.
    float c8a[8], s8a[8];              // s=128: k = 16m + lo
#pragma unroll
    for (int m = 0; m < 8; ++m)
        wrev(-(16.0f * (float)m + lof) * (1.0f / 256.0f), c8a[m], s8a[m]);
    float c4a[4], s4a[4];              // s=64: k = 16m + lo
#pragma unroll
    for (int m = 0; m < 4; ++m)
        wrev(-(16.0f * (float)m + lof) * (1.0f / 128.0f), c4a[m], s4a[m]);
    float c2a[2], s2a[2];              // s=32: k = 16m + lo
#pragma unroll
    for (int m = 0; m < 2; ++m)
        wrev(-(16.0f * (float)m + lof) * (1.0f / 64.0f), c2a[m], s2a[m]);
    float c1a, s1a;                    // s=16: k = lo
    wrev(-lof * (1.0f / 32.0f), c1a, s1a);

    // ---- L1 stages s=1,2,4,8 (reg-local), exact constant twiddles
    const float W8R[8] = {1.f, 0.9238795325112867f, 0.7071067811865476f,
                          0.3826834323650898f, 0.f, -0.3826834323650898f,
                          -0.7071067811865476f, -0.9238795325112867f};
    const float W8I[8] = {0.f, -0.3826834323650898f, -0.7071067811865476f,
                          -0.9238795325112867f, -1.f, -0.9238795325112867f,
                          -0.7071067811865476f, -0.3826834323650898f};
#pragma unroll
    for (int st = 0; st < 4; ++st) {
        const int S = 1 << st;
#pragma unroll
        for (int rl = 0; rl < 16; ++rl) {
            if (rl & S) continue;
            const int k8 = (rl & (S - 1)) * (8 >> st);
            bfly(re[rl], im[rl], re[rl | S], im[rl | S], W8R[k8], W8I[k8]);
        }
    }

    // ---- T1: L1 (e=lane*16+r) -> L3 (e=(lane>>4)*256+r*16+(lane&15))
#pragma unroll
    for (int r = 0; r < 16; ++r) s[pad(lane * 16 + r)] = re[r];
    LDSYNC();
#pragma unroll
    for (int r = 0; r < 16; ++r) re[r] = s[pad(hi + (r << 4) + lo)];
    LDSYNC();
#pragma unroll
    for (int r = 0; r < 16; ++r) s[pad(lane * 16 + r)] = im[r];
    LDSYNC();
#pragma unroll
    for (int r = 0; r < 16; ++r) im[r] = s[pad(hi + (r << 4) + lo)];
    LDSYNC();

    // ---- L3 stages s=16,32,64,128 (twiddles already in registers)
#pragma unroll
    for (int rl = 0; rl < 16; ++rl) if (!(rl & 1))
        bfly(re[rl], im[rl], re[rl|1], im[rl|1], c1a, s1a);
#pragma unroll
    for (int rl = 0; rl < 16; ++rl) if (!(rl & 2))
        bfly(re[rl], im[rl], re[rl|2], im[rl|2], c2a[rl & 1], s2a[rl & 1]);
#pragma unroll
    for (int rl = 0; rl < 16; ++rl) if (!(rl & 4))
        bfly(re[rl], im[rl], re[rl|4], im[rl|4], c4a[rl & 3], s4a[rl & 3]);
#pragma unroll
    for (int rl = 0; rl < 16; ++rl) if (!(rl & 8))
        bfly(re[rl], im[rl], re[rl|8], im[rl|8], c8a[rl & 7], s8a[rl & 7]);

    // ---- L2-stage twiddles, generated before T2 so they overlap DS waits.
    const float lf = (float)lane;
    float cz8[8], sz8[8];              // s=512: k = 64m + lane
#pragma unroll
    for (int m = 0; m < 8; ++m)
        wrev(-(64.0f * (float)m + lf) * (1.0f / 1024.0f), cz8[m], sz8[m]);
    float cz4[4], sz4[4];              // s=256: k = 64m + lane
#pragma unroll
    for (int m = 0; m < 4; ++m)
        wrev(-(64.0f * (float)m + lf) * (1.0f / 512.0f), cz4[m], sz4[m]);

    // ---- T2: L3 -> L2 (e=r*64+lane), split passes
#pragma unroll
    for (int r = 0; r < 16; ++r) s[pad(hi + (r << 4) + lo)] = re[r];
    LDSYNC();
#pragma unroll
    for (int r = 0; r < 16; ++r) re[r] = s[pad((r << 6) + lane)];
    LDSYNC();
#pragma unroll
    for (int r = 0; r < 16; ++r) s[pad(hi + (r << 4) + lo)] = im[r];
    LDSYNC();
#pragma unroll
    for (int r = 0; r < 16; ++r) im[r] = s[pad((r << 6) + lane)];
    LDSYNC();

    // ---- L2 stages s=256,512
#pragma unroll
    for (int rl = 0; rl < 16; ++rl) if (!(rl & 4))
        bfly(re[rl], im[rl], re[rl|4], im[rl|4], cz4[rl & 3], sz4[rl & 3]);
#pragma unroll
    for (int rl = 0; rl < 16; ++rl) if (!(rl & 8))
        bfly(re[rl], im[rl], re[rl|8], im[rl|8], cz8[rl & 7], sz8[rl & 7]);

    // ---- coalesced stores (fixed r -> one contiguous 256B segment)
#pragma unroll
    for (int r = 0; r < 16; ++r) {
        yre[base + (r << 6) + lane] = re[r];
        yim[base + (r << 6) + lane] = im[r];
    }
}

// one-time table: correctly-rounded fl32(log n) and fl32(1/sqrt n), n=1..1024
__global__ __launch_bounds__(256) void table_kernel(float* __restrict__ ws) {
    const int i = (int)(blockIdx.x * 256 + threadIdx.x);
    if (i < 1024) {
        const double nd = (double)(i + 1);
        ws[i]        = (float)log(nd);
        ws[1024 + i] = (float)(1.0 / sqrt(nd));
    }
}

__device__ void z_eval(const float* __restrict__ tin, float* __restrict__ zout,
                       const float* __restrict__ ws, int zblock, int n,
                       float* __restrict__ buf)
{
    // copy 2048-float table ws -> LDS (float4, coalesced)
    for (int i = (int)threadIdx.x; i < 512; i += 256)
        reinterpret_cast<float4*>(buf)[i] = reinterpret_cast<const float4*>(ws)[i];
    __syncthreads();
    const float* slog = buf;
    const float* srsq = buf + 1024;

    const int gid = zblock * 256 + (int)threadIdx.x;
    if (gid >= n) return;

    const float t  = tin[gid];
    const float th = __fmul_rn(t, 0.5f);
    const float logt = (float)log((double)t);
    float theta = __fsub_rn(__fsub_rn(__fmul_rn(th, __fsub_rn(logt, 1.8378770664093453f)), th),
                            0.39269908169872414f);
    theta = __fadd_rn(theta, __fdiv_rn(1.0f, __fmul_rn(48.0f, t)));

    int nt = (int)sqrtf(__fdiv_rn(t, 6.283185307179586f));
    nt = min(max(nt, 10), 1024);

    float acc = 0.0f;
    for (int i = 0; i < nt; ++i) {
        const float p = __fsub_rn(__fmul_rn(t, slog[i]), theta);
        const double rev = (double)p * INV_2PI_D;
        const double fr  = rev - rint(rev);            // |fr| <= 0.5 revolutions
        const float  c   = __builtin_amdgcn_cosf((float)fr);
        acc = __fmaf_rn(srsq[i], c, acc);
    }
    zout[gid] = __fmul_rn(2.0f, acc);
}

__global__ __launch_bounds__(256, 6) void fused_kernel(
    const float* __restrict__ xre, const float* __restrict__ xim,
    const float* __restrict__ tin, const float* __restrict__ ws,
    float* __restrict__ yre, float* __restrict__ yim, float* __restrict__ zout,
    int z_blocks, int nrows, int nz)
{
    __shared__ float s[4][1088];     // 17408 B/block -> 6 blocks/CU

    const int b = (int)blockIdx.x;
    if (b < z_blocks) {
        z_eval(tin, zout, ws, b, nz, &s[0][0]);
    } else {
        const int wid = (int)(threadIdx.x >> 6);
        const int row = ((b - z_blocks) << 2) | wid;
        if (row < nrows)
            fft_row(xre, xim, yre, yim, s[wid], row);
    }
}

extern "C" void kernel_launch(void* const* d_in, const int* in_sizes, int n_in,
                              void* d_out, int out_size, void* d_ws, size_t ws_size,
                              hipStream_t stream)
{
    const float* xre = (const float*)d_in[0];
    const float* xim = (const float*)d_in[1];
    const float* t   = (const float*)d_in[2];

    const size_t nfft = (size_t)in_sizes[0];          // 16384*1024
    const int nrows = (int)(nfft >> 10);              // 16384
    const int nz    = in_sizes[2];                    // 262144

    float* yre = (float*)d_out;
    float* yim = yre + nfft;
    float* z   = yre + 2 * nfft;
    float* ws  = (float*)d_ws;                        // 2048 floats of table

    table_kernel<<<4, 256, 0, stream>>>(ws);

    const int f_blocks = (nrows + 3) >> 2;
    const int z_blocks = (nz + 255) >> 8;
    fused_kernel<<<z_blocks + f_blocks, 256, 0, stream>>>(
        xre, xim, t, ws, yre, yim, z, z_blocks, nrows, nz);
}